// Round 19
// baseline (308.576 us; speedup 1.0000x reference)
//
#include <hip/hip_runtime.h>
#include <hip/hip_bf16.h>
#include <math.h>

#define Hh 48
#define Ww 160
#define NP 7680      // H*W
#define NCH 30       // chunks (non-atomic path)
#define CSZ 256      // gaussians per chunk (compile-time: full unroll, low VGPR)

using bf16 = __hip_bfloat16;
typedef __attribute__((ext_vector_type(8))) short v8s;
typedef __attribute__((ext_vector_type(4))) float v4f;

__device__ __forceinline__ float bfdec(unsigned short u) {
  return __uint_as_float(((unsigned)u) << 16);
}
__device__ __forceinline__ unsigned short bfenc(float x) {
  bf16 b = __float2bfloat16(x);
  return *(unsigned short*)&b;
}
__device__ __forceinline__ float ldany(const void* p, size_t i, int isbf) {
  return isbf ? bfdec(((const unsigned short*)p)[i]) : ((const float*)p)[i];
}

__device__ __forceinline__ int mapidx(int i, int n, int mode) {
  if (mode == 0) return i < 0 ? 0 : (i >= n ? n - 1 : i);       // edge
  return i < 0 ? -i : (i >= n ? 2 * n - 2 - i : i);             // reflect
}

__device__ __forceinline__ float eluf(float v) { return v > 0.f ? v : expm1f(v); }
__device__ __forceinline__ float geluf(float v) {
  float c = v + 0.044715f * v * v * v;
  return 0.5f * v * (1.f + tanhf(0.7978845608028654f * c));
}

// ---------------- dtype sniffer ----------------
__global__ __launch_bounds__(256) void sniff_k(const unsigned short* __restrict__ w,
                                               int* __restrict__ flag) {
  __shared__ int cnt[256];
  int c = 0;
  for (int i = threadIdx.x; i < 2048; i += 256) {
    float a = fabsf(bfdec(w[i]));
    if (a > 1e-3f && a < 0.5f) c++;
  }
  cnt[threadIdx.x] = c;
  __syncthreads();
  for (int s = 128; s > 0; s >>= 1) {
    if (threadIdx.x < s) cnt[threadIdx.x] += cnt[threadIdx.x + s];
    __syncthreads();
  }
  if (threadIdx.x == 0) flag[0] = (cnt[0] > 1536) ? 1 : 0;
}

// ---------------- LDS-tiled transpose: x [128][NP] -> xb bf16 [NP][128] ----------------
__global__ __launch_bounds__(256) void transpose_x_k(const int* __restrict__ flag,
    const void* __restrict__ xsrc, unsigned short* __restrict__ xb) {
  __shared__ float tile[32][33];
  const int f = *flag;
  const int pb = blockIdx.x * 32, cb = blockIdx.y * 32;
#pragma unroll
  for (int pass = 0; pass < 4; pass++) {
    int ci = (threadIdx.x >> 5) + pass * 8, pl = threadIdx.x & 31;
    tile[ci][pl] = ldany(xsrc, (size_t)(cb + ci) * NP + pb + pl, f);
  }
  __syncthreads();
#pragma unroll
  for (int pass = 0; pass < 4; pass++) {
    int pl = (threadIdx.x >> 5) + pass * 8, ci = threadIdx.x & 31;
    xb[(size_t)(pb + pl) * 128 + cb + ci] = bfenc(tile[ci][pl]);
  }
}

// ---------------- merged prep (weights permuted k' = t*C+ci) ----------------
__global__ __launch_bounds__(256) void prep_k(const int* __restrict__ flag,
    const void* disp, const void* invK, const void* K, const void* rw2,
    const void* rb2, const void* sw2, const void* sb2, const void* ow2, const void* ob2,
    const void* rb1, const void* sb1, const void* ob1, const void* fb1, const void* fb2,
    const void* frb, const void* rot_w1, const void* scl_w1, const void* opa_w1,
    const void* fl_w1, const void* fl_w2, const void* fr_w,
    float* __restrict__ dispf, float* __restrict__ smallf, float* __restrict__ biasf,
    unsigned short* __restrict__ a_h1, unsigned short* __restrict__ a_fl1,
    unsigned short* __restrict__ a_fl2, unsigned short* __restrict__ a_fr, int permfr) {
  int i = blockIdx.x * 256 + threadIdx.x;
  int f = *flag;
  if (i < 7680) { dispf[i] = ldany(disp, i, f); return; }
  i -= 7680;
  if (i < 508) {
    const void* src; int off;
    if (i < 16)       { src = invK; off = i; }
    else if (i < 32)  { src = K;    off = i - 16; }
    else if (i < 320) { src = rw2;  off = i - 32; }
    else if (i < 324) { src = rb2;  off = i - 320; }
    else if (i < 486) { src = sw2;  off = i - 324; }
    else if (i < 489) { src = sb2;  off = i - 486; }
    else if (i < 507) { src = ow2;  off = i - 489; }
    else              { src = ob2;  off = i - 507; }
    smallf[i] = ldany(src, off, f); return;
  }
  i -= 508;
  if (i < 336) {
    if (i < 8) biasf[i] = ldany(rb1, i, f);
    else if (i < 14) biasf[i] = ldany(sb1, i - 8, f);
    else if (i < 16) biasf[i] = ldany(ob1, i - 14, f);
    else if (i < 144) biasf[i] = ldany(fb1, i - 16, f);
    else if (i < 208) biasf[i] = ldany(fb2, i - 144, f);
    else biasf[i] = ldany(frb, i - 208, f);
    return;
  }
  i -= 336;
  if (i < 73728) {   // a_h1 permuted (C=128)
    int co = i / 1152, rem = i - co * 1152;
    int t = rem >> 7, ci = rem & 127;
    float v = 0.f;
    if (co < 8) v = ldany(rot_w1, (size_t)co * 1152 + ci * 9 + t, f);
    else if (co < 14) v = ldany(scl_w1, (size_t)(co - 8) * 1152 + ci * 9 + t, f);
    else if (co < 16) v = ldany(opa_w1, (size_t)(co - 14) * 1152 + ci * 9 + t, f);
    a_h1[i] = bfenc(v); return;
  }
  i -= 73728;
  if (i < 147456) {
    int co = i / 1152, rem = i - co * 1152;
    int t = rem >> 7, ci = rem & 127;
    a_fl1[i] = bfenc(ldany(fl_w1, (size_t)co * 1152 + ci * 9 + t, f)); return;
  }
  i -= 147456;
  if (i < 73728) {
    int co = i / 1152, rem = i - co * 1152;
    int t = rem >> 7, ci = rem & 127;
    a_fl2[i] = bfenc(ldany(fl_w2, (size_t)co * 1152 + ci * 9 + t, f)); return;
  }
  i -= 73728;
  if (i < 73728) {
    if (permfr) {
      int co = i / 576, rem = i - co * 576;
      int t = rem >> 6, ci = rem & 63;
      a_fr[i] = bfenc(ldany(fr_w, (size_t)co * 576 + ci * 9 + t, f));
    } else {
      a_fr[i] = bfenc(ldany(fr_w, i, f));
    }
    return;
  }
}

// ---------------- MFMA conv, 4 waves x (16co x 64px) ----------------
template<int OM, int PM, int ACT, bool GUARD, int KP, bool OPX>
__global__ __launch_bounds__(256) void gemm_conv4_k(const unsigned short* __restrict__ A,
    const unsigned short* __restrict__ X, const float* __restrict__ bias,
    void* __restrict__ out, const int* __restrict__ flag, int K, int glim) {
  __shared__ v8s As4[64][5];
  __shared__ v8s Bs4[64][5];
  __shared__ int off9s[64][9];
  const int tid = threadIdx.x;
  const int pxB = blockIdx.x * 64;
  const int coB = blockIdx.y * 64;
  if (tid < 64) {
    int p = pxB + tid;
    int h = p / Ww, w = p - h * Ww;
#pragma unroll
    for (int r = 0; r < 3; r++) {
      int hh = mapidx(h + r - 1, Hh, PM);
#pragma unroll
      for (int s = 0; s < 3; s++)
        off9s[tid][r * 3 + s] = hh * Ww + mapidx(w + s - 1, Ww, PM);
    }
  }
  const int lane = tid & 63, wv = tid >> 6;
  const int m16 = lane & 15, quad = lane >> 4;
  const int srow = tid >> 2, sg = tid & 3;
  v4f acc[4];
#pragma unroll
  for (int b = 0; b < 4; b++) acc[b] = (v4f){0.f, 0.f, 0.f, 0.f};
  __syncthreads();
  const int nIter = K >> 5;
  for (int it = 0; it < nIter; it++) {
    const int k0 = it << 5;
    {
      const unsigned short* ap = &A[(size_t)(coB + srow) * K + k0 + sg * 8];
      v8s av;
#pragma unroll
      for (int j = 0; j < 8; j++) av[j] = (short)ap[j];
      As4[srow][sg] = av;
    }
    {
      v8s bv;
      if (KP == 128) {
        int kk = k0 + sg * 8;
        int t = kk >> 7, c0 = kk & 127;
        const unsigned short* xp = &X[(size_t)off9s[srow][t] * 128 + c0];
#pragma unroll
        for (int j = 0; j < 8; j++) bv[j] = (short)xp[j];
      } else if (KP == 64) {
        int kk = k0 + sg * 8;
        int t = kk >> 6, c0 = kk & 63;
        const unsigned short* xp = &X[(size_t)off9s[srow][t] * 64 + c0];
#pragma unroll
        for (int j = 0; j < 8; j++) bv[j] = (short)xp[j];
      } else {
#pragma unroll
        for (int j = 0; j < 8; j++) {
          int k = k0 + sg * 8 + j;
          int ci = k / 9;
          int t = k - ci * 9;
          bv[j] = (short)X[(size_t)ci * NP + off9s[srow][t]];
        }
      }
      Bs4[srow][sg] = bv;
    }
    __syncthreads();
    v8s af = As4[wv * 16 + m16][quad];
    v8s bfr[4];
#pragma unroll
    for (int b = 0; b < 4; b++) bfr[b] = Bs4[b * 16 + m16][quad];
#pragma unroll
    for (int b = 0; b < 4; b++)
      acc[b] = __builtin_amdgcn_mfma_f32_16x16x32_bf16(af, bfr[b], acc[b], 0, 0, 0);
    __syncthreads();
  }
  const int obf = (OM == 2) ? *flag : (OM == 1);
#pragma unroll
  for (int b = 0; b < 4; b++) {
#pragma unroll
    for (int r = 0; r < 4; r++) {
      int co = coB + wv * 16 + quad * 4 + r;
      int px = pxB + b * 16 + m16;
      if (GUARD && co >= glim) continue;
      float bv = bias[GUARD ? (co & 15) : co];
      float v = acc[b][r] + bv;
      v = (ACT == 2) ? geluf(v) : eluf(v);
      size_t oi = OPX ? ((size_t)px * 128 + co) : ((size_t)co * NP + px);
      if (obf) ((unsigned short*)out)[oi] = bfenc(v);
      else ((float*)out)[oi] = v;
    }
  }
}

// ---------------- fused fl1 + head conv ----------------
__global__ __launch_bounds__(256) void conv_fused1_k(
    const unsigned short* __restrict__ a_fl1, const unsigned short* __restrict__ a_h1,
    const unsigned short* __restrict__ X, const float* __restrict__ biasf,
    unsigned short* __restrict__ t1b, float* __restrict__ h1) {
  __shared__ v8s As4[64][5];
  __shared__ v8s Bs4[64][5];
  __shared__ int off9s[64][9];
  const int tid = threadIdx.x;
  const int zy = blockIdx.y;
  const bool ishead = (zy == 2);
  const int pm = ishead ? 0 : 1;
  const int pxB = blockIdx.x * 64;
  const int coB = ishead ? 0 : zy * 64;
  const unsigned short* A = ishead ? a_h1 : a_fl1;
  if (tid < 64) {
    int p = pxB + tid;
    int h = p / Ww, w = p - h * Ww;
#pragma unroll
    for (int r = 0; r < 3; r++) {
      int hh = mapidx(h + r - 1, Hh, pm);
#pragma unroll
      for (int s = 0; s < 3; s++)
        off9s[tid][r * 3 + s] = hh * Ww + mapidx(w + s - 1, Ww, pm);
    }
  }
  const int lane = tid & 63, wv = tid >> 6;
  const int m16 = lane & 15, quad = lane >> 4;
  const int srow = tid >> 2, sg = tid & 3;
  v4f acc[4];
#pragma unroll
  for (int b = 0; b < 4; b++) acc[b] = (v4f){0.f, 0.f, 0.f, 0.f};
  __syncthreads();
  for (int it = 0; it < 36; it++) {
    const int k0 = it << 5;
    {
      const unsigned short* ap = &A[(size_t)(coB + srow) * 1152 + k0 + sg * 8];
      v8s av;
#pragma unroll
      for (int j = 0; j < 8; j++) av[j] = (short)ap[j];
      As4[srow][sg] = av;
    }
    {
      int kk = k0 + sg * 8;
      int t = kk >> 7, c0 = kk & 127;
      const unsigned short* xp = &X[(size_t)off9s[srow][t] * 128 + c0];
      v8s bv;
#pragma unroll
      for (int j = 0; j < 8; j++) bv[j] = (short)xp[j];
      Bs4[srow][sg] = bv;
    }
    __syncthreads();
    v8s af = As4[wv * 16 + m16][quad];
    v8s bfr[4];
#pragma unroll
    for (int b = 0; b < 4; b++) bfr[b] = Bs4[b * 16 + m16][quad];
#pragma unroll
    for (int b = 0; b < 4; b++)
      acc[b] = __builtin_amdgcn_mfma_f32_16x16x32_bf16(af, bfr[b], acc[b], 0, 0, 0);
    __syncthreads();
  }
#pragma unroll
  for (int b = 0; b < 4; b++) {
#pragma unroll
    for (int r = 0; r < 4; r++) {
      int co = coB + wv * 16 + quad * 4 + r;
      int px = pxB + b * 16 + m16;
      if (ishead) {
        if (co < 16) h1[(size_t)co * NP + px] = geluf(acc[b][r] + biasf[co]);
      } else {
        t1b[(size_t)px * 128 + co] = bfenc(eluf(acc[b][r] + biasf[16 + co]));
      }
    }
  }
}

// ---------------- head2 + per-gaussian prep ----------------
__global__ __launch_bounds__(64) void head2_prep_k(const float* __restrict__ h1,
    const float* __restrict__ smallf, const float* __restrict__ dispf,
    float* __restrict__ params, float* __restrict__ zbuf, int* __restrict__ rank) {
  const float* invK = smallf;
  const float* Km   = smallf + 16;
  const float* rw2  = smallf + 32;
  const float* rb2  = smallf + 320;
  const float* sw2  = smallf + 324;
  const float* sb2  = smallf + 486;
  const float* ow2  = smallf + 489;
  const float* ob2  = smallf + 507;
  int p = blockIdx.x * 64 + threadIdx.x;
  if (p >= NP) return;
  int hh = p / Ww, ww = p - hh * Ww;
  float racc[4], sacc[3], oacc;
#pragma unroll
  for (int i = 0; i < 4; i++) racc[i] = rb2[i];
#pragma unroll
  for (int i = 0; i < 3; i++) sacc[i] = sb2[i];
  oacc = ob2[0];
  for (int ci = 0; ci < 16; ci++) {
    float t9[9];
#pragma unroll
    for (int r = 0; r < 3; r++) {
      int rr = mapidx(hh + r - 1, Hh, 0);
#pragma unroll
      for (int s = 0; s < 3; s++) {
        int cc = mapidx(ww + s - 1, Ww, 0);
        t9[r * 3 + s] = h1[(size_t)ci * NP + rr * Ww + cc];
      }
    }
    if (ci < 8) {
      for (int co = 0; co < 4; co++)
#pragma unroll
        for (int k = 0; k < 9; k++)
          racc[co] = fmaf(t9[k], rw2[(co * 8 + ci) * 9 + k], racc[co]);
    } else if (ci < 14) {
      int c2 = ci - 8;
      for (int co = 0; co < 3; co++)
#pragma unroll
        for (int k = 0; k < 9; k++)
          sacc[co] = fmaf(t9[k], sw2[(co * 6 + c2) * 9 + k], sacc[co]);
    } else {
      int c2 = ci - 14;
#pragma unroll
      for (int k = 0; k < 9; k++)
        oacc = fmaf(t9[k], ow2[c2 * 9 + k], oacc);
    }
  }
  float nq = sqrtf(racc[0]*racc[0] + racc[1]*racc[1] + racc[2]*racc[2] + racc[3]*racc[3]);
  nq = fmaxf(nq, 1e-12f);
  float qw = racc[0] / nq, qx = racc[1] / nq, qy = racc[2] / nq, qz = racc[3] / nq;
  float s0 = fabsf(sacc[0]), s1 = fabsf(sacc[1]), s2 = fabsf(sacc[2]);
  float opa = 1.f / (1.f + __expf(-oacc));
  float d = dispf[p];
  float scaled = 0.01f + 9.99f * d;
  float depth = fminf(fmaxf(1.f / scaled, 0.1f), 100.f);
  float M00 = invK[0], M01 = invK[1], M02 = invK[2];
  float M10 = invK[4], M11 = invK[5], M12 = invK[6];
  float M20 = invK[8], M21 = invK[9], M22 = invK[10];
  float gxf = (float)ww, gyf = (float)hh;
  float X = (M00 * gxf + M01 * gyf + M02) * depth;
  float Y = (M10 * gxf + M11 * gyf + M12) * depth;
  float Z = (M20 * gxf + M21 * gyf + M22) * depth;
  float fxk = Km[0], fyk = Km[5];
  float cxk = Km[2], cyk = Km[6];
  float u = fxk * X / Z + cxk;
  float v = fyk * Y / Z + cyk;
  float R00 = 1.f - 2.f*(qy*qy + qz*qz), R01 = 2.f*(qx*qy - qw*qz), R02 = 2.f*(qx*qz + qw*qy);
  float R10 = 2.f*(qx*qy + qw*qz), R11 = 1.f - 2.f*(qx*qx + qz*qz), R12 = 2.f*(qy*qz - qw*qx);
  float R20 = 2.f*(qx*qz - qw*qy), R21 = 2.f*(qy*qz + qw*qx), R22 = 1.f - 2.f*(qx*qx + qy*qy);
  float M0a = R00*s0, M0b = R01*s1, M0c = R02*s2;
  float M1a = R10*s0, M1b = R11*s1, M1c = R12*s2;
  float M2a = R20*s0, M2b = R21*s1, M2c = R22*s2;
  float S00 = M0a*M0a + M0b*M0b + M0c*M0c;
  float S01 = M0a*M1a + M0b*M1b + M0c*M1c;
  float S02 = M0a*M2a + M0b*M2b + M0c*M2c;
  float S11 = M1a*M1a + M1b*M1b + M1c*M1c;
  float S12 = M1a*M2a + M1b*M2b + M1c*M2c;
  float S22 = M2a*M2a + M2b*M2b + M2c*M2c;
  float iz = 1.f / Z;
  float j00 = fxk * iz, j02 = -fxk * X * iz * iz;
  float j11 = fyk * iz, j12 = -fyk * Y * iz * iz;
  float c00 = j00*j00*S00 + 2.f*j00*j02*S02 + j02*j02*S22 + 0.3f;
  float c01 = j00*j11*S01 + j00*j12*S02 + j02*j11*S12 + j02*j12*S22;
  float c11 = j11*j11*S11 + 2.f*j11*j12*S12 + j12*j12*S22 + 0.3f;
  float det = c00 * c11 - c01 * c01;
  float idet = 1.f / det;
  float* pr = params + (size_t)p * 8;
  pr[0] = u; pr[1] = v; pr[2] = c11 * idet; pr[3] = -c01 * idet;
  pr[4] = c00 * idet; pr[5] = opa; pr[6] = Z; pr[7] = 0.f;
  zbuf[p] = Z;
  rank[p] = 0;
}

// ---------------- rank-by-count stable argsort ----------------
__global__ __launch_bounds__(256) void rank_count_k(const float* __restrict__ zbuf,
                                                    int* __restrict__ rank) {
  int i = blockIdx.x * 256 + threadIdx.x;
  int sid = blockIdx.y;
  float zi = zbuf[i];
  const float4* zv = (const float4*)(zbuf + sid * 960);
  int cnt = 0;
  for (int t = 0; t < 240; t++) {
    float4 z4 = zv[t];
    int jb = sid * 960 + t * 4;
    cnt += (z4.x < zi || (z4.x == zi && jb + 0 < i)) ? 1 : 0;
    cnt += (z4.y < zi || (z4.y == zi && jb + 1 < i)) ? 1 : 0;
    cnt += (z4.z < zi || (z4.z == zi && jb + 2 < i)) ? 1 : 0;
    cnt += (z4.w < zi || (z4.w == zi && jb + 3 < i)) ? 1 : 0;
  }
  atomicAdd(&rank[i], cnt);
}

__global__ __launch_bounds__(256) void scatter_k(const int* __restrict__ rank,
                                                 int* __restrict__ ord) {
  int i = blockIdx.x * 256 + threadIdx.x;
  ord[rank[i]] = i;
}

// params transform: exp2-domain conic. c==2/4: *-0.5*log2e; c==3: *-log2e.
__device__ __forceinline__ float ptransform(float v, int c) {
  if (c == 2 || c == 4) return v * -0.72134752f;
  if (c == 3) return v * -1.44269504f;
  return v;
}

// ---------------- fused gather (non-atomic): featT bf16 + transformed params ----------------
__global__ __launch_bounds__(256) void gather_all_k(const int* __restrict__ ord,
    const float* __restrict__ t2e, const float* __restrict__ params,
    unsigned short* __restrict__ featT, float* __restrict__ params_s) {
  int gid = blockIdx.x * 256 + threadIdx.x;
  if (gid < NP * 64) {
    int c = gid / NP, n = gid - c * NP;
    featT[gid] = bfenc(t2e[(size_t)c * NP + ord[n]]);
  } else {
    int g2 = gid - NP * 64;
    int n = g2 >> 3, c = g2 & 7;
    params_s[g2] = ptransform(params[((size_t)ord[n] << 3) + c], c);
  }
}

// ---------------- gather (atomic fallback) ----------------
__global__ __launch_bounds__(256) void gather_k(const int* __restrict__ ord,
    const float* __restrict__ params, const float* __restrict__ t2e,
    float* __restrict__ params_s, float* __restrict__ feat_s, float* levz) {
  int gid = blockIdx.x * 256 + threadIdx.x;   // NP*64
  int n = gid >> 6, c = gid & 63;
  int orig = ord[n];
  feat_s[gid] = t2e[(size_t)c * NP + orig];
  if (levz) levz[gid] = 0.f;
  if (c < 8) params_s[(n << 3) + c] = ptransform(params[((size_t)orig << 3) + c], c);
}

// ---------------- MFMA raster: 2 indep waves/block, compile-time CSZ ----------------
// grid (NP/128, NCH), block 128. partial [chunk][px][64ch]; tch[chunk][px].
__global__ __launch_bounds__(128) void raster_mfma_k(const float* __restrict__ params_s,
    const unsigned short* __restrict__ featT, float* __restrict__ partial,
    float* __restrict__ tch) {
  __shared__ unsigned int Wl[2][64][17];
  const int tid = threadIdx.x;
  const int lane = tid & 63, wv = tid >> 6;
  const int m16 = lane & 15, quad = lane >> 4;
  const int ch = blockIdx.y;
  const int g0 = ch * CSZ;
  const int pxB = blockIdx.x * 128;
  const int mypx = pxB + wv * 64 + lane;
  const float px = (float)(mypx % Ww), py = (float)(mypx / Ww);
  float T = 1.f;
  v4f acc[4][4];
#pragma unroll
  for (int a = 0; a < 4; a++)
#pragma unroll
    for (int b = 0; b < 4; b++) acc[a][b] = (v4f){0.f, 0.f, 0.f, 0.f};
  const float4* pv = (const float4*)params_s + (size_t)g0 * 2;
  for (int sub = 0; sub < CSZ / 32; sub++) {
    float al[32];
#pragma unroll
    for (int j = 0; j < 32; j++) {
      float4 pa = pv[(sub * 32 + j) * 2], pb = pv[(sub * 32 + j) * 2 + 1];
      float dx = px - pa.x, dy = py - pa.y;
      float power = fmaf(dx * dx, pa.z, fmaf(dy * dy, pb.x, dx * dy * pa.w));
      al[j] = fminf(pb.y * __builtin_amdgcn_exp2f(power), 0.99f);
    }
#pragma unroll
    for (int jj = 0; jj < 16; jj++) {
      float w0 = al[2 * jj] * T;     T *= 1.f - al[2 * jj];
      float w1 = al[2 * jj + 1] * T; T *= 1.f - al[2 * jj + 1];
      Wl[wv][lane][jj] = (unsigned)bfenc(w0) | ((unsigned)bfenc(w1) << 16);
    }
    v8s af[4], bfr[4];
#pragma unroll
    for (int a = 0; a < 4; a++) {
      unsigned d0 = Wl[wv][a * 16 + m16][quad * 4 + 0];
      unsigned d1 = Wl[wv][a * 16 + m16][quad * 4 + 1];
      unsigned d2 = Wl[wv][a * 16 + m16][quad * 4 + 2];
      unsigned d3 = Wl[wv][a * 16 + m16][quad * 4 + 3];
      v8s t;
      t[0] = (short)(d0 & 0xffff); t[1] = (short)(d0 >> 16);
      t[2] = (short)(d1 & 0xffff); t[3] = (short)(d1 >> 16);
      t[4] = (short)(d2 & 0xffff); t[5] = (short)(d2 >> 16);
      t[6] = (short)(d3 & 0xffff); t[7] = (short)(d3 >> 16);
      af[a] = t;
    }
#pragma unroll
    for (int b = 0; b < 4; b++) {
      const unsigned short* fp = &featT[(size_t)(b * 16 + m16) * NP + g0 + sub * 32 + quad * 8];
      v8s t;
#pragma unroll
      for (int j = 0; j < 8; j++) t[j] = (short)fp[j];
      bfr[b] = t;
    }
#pragma unroll
    for (int a = 0; a < 4; a++)
#pragma unroll
      for (int b = 0; b < 4; b++)
        acc[a][b] = __builtin_amdgcn_mfma_f32_16x16x32_bf16(af[a], bfr[b], acc[a][b], 0, 0, 0);
  }
  float* pbase = partial + (size_t)ch * NP * 64 + (size_t)(pxB + wv * 64) * 64;
#pragma unroll
  for (int a = 0; a < 4; a++) {
#pragma unroll
    for (int b = 0; b < 4; b++) {
#pragma unroll
      for (int r = 0; r < 4; r++) {
        pbase[(size_t)(a * 16 + quad * 4 + r) * 64 + b * 16 + m16] = acc[a][b][r];
      }
    }
  }
  tch[(size_t)ch * NP + mypx] = T;
}

// ---------------- alpha (atomic fallback only) ----------------
__global__ __launch_bounds__(256) void alpha_k(const float* __restrict__ params_s,
    float* __restrict__ tch, int chsz) {
  const int p = blockIdx.x * 256 + threadIdx.x;
  const int ch = blockIdx.y;
  const float px = (float)(p % Ww), py = (float)(p / Ww);
  float T = 1.f;
  const float4* pv = (const float4*)params_s + (size_t)ch * chsz * 2;
  for (int n0 = 0; n0 < chsz; n0++) {
    float4 pa = pv[n0 * 2], pb = pv[n0 * 2 + 1];
    float dx = px - pa.x, dy = py - pa.y;
    float power = fmaf(dx * dx, pa.z, fmaf(dy * dy, pb.x, dx * dy * pa.w));
    float al = fminf(pb.y * __builtin_amdgcn_exp2f(power), 0.99f);
    T *= 1.f - al;
  }
  tch[(size_t)ch * NP + p] = T;
}

// ---------------- prefix products (atomic fallback only) ----------------
__global__ __launch_bounds__(256) void tpre_k(const float* __restrict__ tch,
    float* __restrict__ tpre, int nchunk) {
  int p = blockIdx.x * 256 + threadIdx.x;
  float T = 1.f;
  for (int ch = 0; ch < nchunk; ch++) {
    tpre[(size_t)ch * NP + p] = T;
    T *= tch[(size_t)ch * NP + p];
  }
}

// ---------------- atomic-fallback raster ----------------
__global__ __launch_bounds__(128) void raster_atomic_k(const float* __restrict__ params_s,
    const float* __restrict__ feat_s, const float* __restrict__ tpre,
    float* __restrict__ lev, int chsz) {
  const int p = blockIdx.x * 128 + threadIdx.x;
  const int ch = blockIdx.y;
  const float px = (float)(p % Ww), py = (float)(p / Ww);
  float4 acc[16];
#pragma unroll
  for (int q = 0; q < 16; q++) acc[q] = make_float4(0.f, 0.f, 0.f, 0.f);
  float T = 1.f;
  const int g0 = ch * chsz;
  const float4* pv = (const float4*)params_s + (size_t)g0 * 2;
  for (int n0 = 0; n0 < chsz; n0++) {
    float4 pa = pv[n0 * 2], pb = pv[n0 * 2 + 1];
    float dx = px - pa.x, dy = py - pa.y;
    float power = fmaf(dx * dx, pa.z, fmaf(dy * dy, pb.x, dx * dy * pa.w));
    float al = fminf(pb.y * __builtin_amdgcn_exp2f(power), 0.99f);
    float wgt = al * T;
    T *= 1.f - al;
    const float4* fr = (const float4*)(feat_s + (((size_t)(g0 + n0)) << 6));
#pragma unroll
    for (int q = 0; q < 16; q++) {
      float4 f = fr[q];
      acc[q].x = fmaf(wgt, f.x, acc[q].x);
      acc[q].y = fmaf(wgt, f.y, acc[q].y);
      acc[q].z = fmaf(wgt, f.z, acc[q].z);
      acc[q].w = fmaf(wgt, f.w, acc[q].w);
    }
  }
  float Ts = tpre[(size_t)ch * NP + p];
#pragma unroll
  for (int q = 0; q < 16; q++) {
    atomicAdd(&lev[(size_t)(q * 4 + 0) * NP + p], Ts * acc[q].x);
    atomicAdd(&lev[(size_t)(q * 4 + 1) * NP + p], Ts * acc[q].y);
    atomicAdd(&lev[(size_t)(q * 4 + 2) * NP + p], Ts * acc[q].z);
    atomicAdd(&lev[(size_t)(q * 4 + 3) * NP + p], Ts * acc[q].w);
  }
}

// ---------------- combine with inline prefix -> px-major bf16 levb ----------------
__global__ __launch_bounds__(256) void combine_k(const float* __restrict__ partial,
    const float* __restrict__ tch, unsigned short* __restrict__ levb) {
  int gid = blockIdx.x * 256 + threadIdx.x;   // 64*NP, gid = p*64 + c
  int p = gid >> 6;
  float T = 1.f, s = 0.f;
  for (int ch = 0; ch < NCH; ch++) {
    s = fmaf(T, partial[(size_t)ch * NP * 64 + gid], s);
    T *= tch[(size_t)ch * NP + p];
  }
  levb[gid] = bfenc(s);
}

// ---------------- lev fp32 -> ch-major bf16 (atomic path) ----------------
__global__ __launch_bounds__(256) void cvt_lev_k(const float* __restrict__ lev,
                                                 unsigned short* __restrict__ levb) {
  int i = blockIdx.x * 256 + threadIdx.x;
  levb[i] = bfenc(lev[i]);
}

extern "C" void kernel_launch(void* const* d_in, const int* in_sizes, int n_in,
                              void* d_out, int out_size, void* d_ws, size_t ws_size,
                              hipStream_t stream) {
  (void)in_sizes; (void)n_in; (void)out_size;
  const void* init_feature = d_in[0];
  const void* disp   = d_in[1];
  const void* invK   = d_in[2];
  const void* Km     = d_in[3];
  const void* rot_w1 = d_in[4];
  const void* rot_b1 = d_in[5];
  const void* rot_w2 = d_in[6];
  const void* rot_b2 = d_in[7];
  const void* scl_w1 = d_in[8];
  const void* scl_b1 = d_in[9];
  const void* scl_w2 = d_in[10];
  const void* scl_b2 = d_in[11];
  const void* opa_w1 = d_in[12];
  const void* opa_b1 = d_in[13];
  const void* opa_w2 = d_in[14];
  const void* opa_b2 = d_in[15];
  const void* fl_w1  = d_in[16];
  const void* fl_b1  = d_in[17];
  const void* fl_w2  = d_in[18];
  const void* fl_b2  = d_in[19];
  const void* fr_w   = d_in[20];
  const void* fr_b   = d_in[21];

  float* wsf = (float*)d_ws;
  int*   flag    = (int*)wsf;                   // @0        16
  float* smallf  = wsf + 16;                    // 512
  float* dispf   = wsf + 528;                   // 7680
  float* biasf   = wsf + 8208;                  // 512
  unsigned short* a_h1  = (unsigned short*)(wsf + 8720);    // 36864 f
  unsigned short* a_fl1 = (unsigned short*)(wsf + 45584);   // 73728 f
  unsigned short* a_fl2 = (unsigned short*)(wsf + 119312);  // 36864 f
  unsigned short* a_fr  = (unsigned short*)(wsf + 156176);  // 36864 f
  unsigned short* xb    = (unsigned short*)(wsf + 193040);  // 491520 f
  unsigned short* t1b   = (unsigned short*)(wsf + 684560);  // 491520 f ([px][128])
  float* t2e     = wsf + 1176080;               // 491520 ([c][px])
  float* h1      = wsf + 1667600;               // 122880
  float* params  = wsf + 1790480;               // 61440
  float* params_s= wsf + 1851920;               // 61440
  float* featbuf = wsf + 1913360;               // 491520 (featT bf16 | feat_s fp32)
  float* tch     = wsf + 2404880;               // 245760
  float* tpre    = wsf + 2650640;               // 245760 (fallback only)
  unsigned short* levb = (unsigned short*)(wsf + 2896400);  // 245760 f
  float* zbuf    = wsf + 3142160;               // 7680
  int*   rank    = (int*)(wsf + 3149840);       // 7680
  int*   ord     = (int*)(wsf + 3157520);       // 7680
  float* lev     = wsf + 3165200;               // 491520 (atomic) / partial base
  float* partial = lev;                         // non-atomic: NCH*64*NP f

  const size_t needNA = (size_t)(3165200 + (size_t)NCH * 64 * NP) * 4;  // 71.6 MB
  const int nonatomic = (ws_size >= needNA) ? 1 : 0;

  sniff_k<<<1, 256, 0, stream>>>((const unsigned short*)fl_w1, flag);
  transpose_x_k<<<dim3(240, 4), 256, 0, stream>>>(flag, init_feature, xb);
  prep_k<<<1474, 256, 0, stream>>>(flag,
      disp, invK, Km, rot_w2, rot_b2, scl_w2, scl_b2, opa_w2, opa_b2,
      rot_b1, scl_b1, opa_b1, fl_b1, fl_b2, fr_b,
      rot_w1, scl_w1, opa_w1, fl_w1, fl_w2, fr_w,
      dispf, smallf, biasf, a_h1, a_fl1, a_fl2, a_fr, nonatomic);

  // fused fl1 + head conv (one dispatch), then fl2
  conv_fused1_k<<<dim3(120, 3), 256, 0, stream>>>(a_fl1, a_h1, xb, biasf, t1b, h1);
  gemm_conv4_k<0, 1, 1, false, 128, false><<<dim3(120, 1), 256, 0, stream>>>(
      a_fl2, t1b, biasf + 144, t2e, flag, 1152, 64);
  head2_prep_k<<<120, 64, 0, stream>>>(h1, smallf, dispf, params, zbuf, rank);
  rank_count_k<<<dim3(30, 8), 256, 0, stream>>>(zbuf, rank);
  scatter_k<<<30, 256, 0, stream>>>(rank, ord);

  if (nonatomic) {
    gather_all_k<<<(NP * 72) / 256, 256, 0, stream>>>(ord, t2e, params,
        (unsigned short*)featbuf, params_s);
    raster_mfma_k<<<dim3(NP / 128, NCH), 128, 0, stream>>>(params_s,
        (const unsigned short*)featbuf, partial, tch);
    combine_k<<<(NP * 64) / 256, 256, 0, stream>>>(partial, tch, levb);
    gemm_conv4_k<2, 1, 1, false, 64, false><<<dim3(120, 2), 256, 0, stream>>>(
        a_fr, levb, biasf + 208, d_out, flag, 576, 128);
  } else {
    gather_k<<<(NP * 64) / 256, 256, 0, stream>>>(ord, params, t2e, params_s,
                                                  featbuf, lev);
    alpha_k<<<dim3(NP / 256, 32), 256, 0, stream>>>(params_s, tch, 240);
    tpre_k<<<30, 256, 0, stream>>>(tch, tpre, 32);
    raster_atomic_k<<<dim3(NP / 128, 32), 128, 0, stream>>>(params_s, featbuf,
                                                            tpre, lev, 240);
    cvt_lev_k<<<1920, 256, 0, stream>>>(lev, levb);
    gemm_conv4_k<2, 1, 1, false, 0, false><<<dim3(120, 2), 256, 0, stream>>>(
        a_fr, levb, biasf + 208, d_out, flag, 576, 128);
  }
}

// Round 20
// 294.450 us; speedup vs baseline: 1.0480x; 1.0480x over previous
//
#include <hip/hip_runtime.h>
#include <hip/hip_bf16.h>
#include <math.h>

#define Hh 48
#define Ww 160
#define NP 7680      // H*W
#define NCH 30       // chunks (non-atomic path)
#define CSZ 256      // gaussians per chunk (compile-time: full unroll, low VGPR)

using bf16 = __hip_bfloat16;
typedef __attribute__((ext_vector_type(8))) short v8s;
typedef __attribute__((ext_vector_type(4))) float v4f;

__device__ __forceinline__ float bfdec(unsigned short u) {
  return __uint_as_float(((unsigned)u) << 16);
}
__device__ __forceinline__ unsigned short bfenc(float x) {
  bf16 b = __float2bfloat16(x);
  return *(unsigned short*)&b;
}
__device__ __forceinline__ float ldany(const void* p, size_t i, int isbf) {
  return isbf ? bfdec(((const unsigned short*)p)[i]) : ((const float*)p)[i];
}

__device__ __forceinline__ int mapidx(int i, int n, int mode) {
  if (mode == 0) return i < 0 ? 0 : (i >= n ? n - 1 : i);       // edge
  return i < 0 ? -i : (i >= n ? 2 * n - 2 - i : i);             // reflect
}

__device__ __forceinline__ float eluf(float v) { return v > 0.f ? v : expm1f(v); }
__device__ __forceinline__ float geluf(float v) {
  float c = v + 0.044715f * v * v * v;
  return 0.5f * v * (1.f + tanhf(0.7978845608028654f * c));
}

// ---------------- dtype sniffer ----------------
__global__ __launch_bounds__(256) void sniff_k(const unsigned short* __restrict__ w,
                                               int* __restrict__ flag) {
  __shared__ int cnt[256];
  int c = 0;
  for (int i = threadIdx.x; i < 2048; i += 256) {
    float a = fabsf(bfdec(w[i]));
    if (a > 1e-3f && a < 0.5f) c++;
  }
  cnt[threadIdx.x] = c;
  __syncthreads();
  for (int s = 128; s > 0; s >>= 1) {
    if (threadIdx.x < s) cnt[threadIdx.x] += cnt[threadIdx.x + s];
    __syncthreads();
  }
  if (threadIdx.x == 0) flag[0] = (cnt[0] > 1536) ? 1 : 0;
}

// ---------------- LDS-tiled transpose: x [128][NP] -> xb bf16 [NP][128] ----------------
__global__ __launch_bounds__(256) void transpose_x_k(const int* __restrict__ flag,
    const void* __restrict__ xsrc, unsigned short* __restrict__ xb) {
  __shared__ float tile[32][33];
  const int f = *flag;
  const int pb = blockIdx.x * 32, cb = blockIdx.y * 32;
#pragma unroll
  for (int pass = 0; pass < 4; pass++) {
    int ci = (threadIdx.x >> 5) + pass * 8, pl = threadIdx.x & 31;
    tile[ci][pl] = ldany(xsrc, (size_t)(cb + ci) * NP + pb + pl, f);
  }
  __syncthreads();
#pragma unroll
  for (int pass = 0; pass < 4; pass++) {
    int pl = (threadIdx.x >> 5) + pass * 8, ci = threadIdx.x & 31;
    xb[(size_t)(pb + pl) * 128 + cb + ci] = bfenc(tile[ci][pl]);
  }
}

// ---------------- merged prep (weights permuted k' = t*C+ci) ----------------
__global__ __launch_bounds__(256) void prep_k(const int* __restrict__ flag,
    const void* disp, const void* invK, const void* K, const void* rw2,
    const void* rb2, const void* sw2, const void* sb2, const void* ow2, const void* ob2,
    const void* rb1, const void* sb1, const void* ob1, const void* fb1, const void* fb2,
    const void* frb, const void* rot_w1, const void* scl_w1, const void* opa_w1,
    const void* fl_w1, const void* fl_w2, const void* fr_w,
    float* __restrict__ dispf, float* __restrict__ smallf, float* __restrict__ biasf,
    unsigned short* __restrict__ a_h1, unsigned short* __restrict__ a_fl1,
    unsigned short* __restrict__ a_fl2, unsigned short* __restrict__ a_fr, int permfr) {
  int i = blockIdx.x * 256 + threadIdx.x;
  int f = *flag;
  if (i < 7680) { dispf[i] = ldany(disp, i, f); return; }
  i -= 7680;
  if (i < 508) {
    const void* src; int off;
    if (i < 16)       { src = invK; off = i; }
    else if (i < 32)  { src = K;    off = i - 16; }
    else if (i < 320) { src = rw2;  off = i - 32; }
    else if (i < 324) { src = rb2;  off = i - 320; }
    else if (i < 486) { src = sw2;  off = i - 324; }
    else if (i < 489) { src = sb2;  off = i - 486; }
    else if (i < 507) { src = ow2;  off = i - 489; }
    else              { src = ob2;  off = i - 507; }
    smallf[i] = ldany(src, off, f); return;
  }
  i -= 508;
  if (i < 336) {
    if (i < 8) biasf[i] = ldany(rb1, i, f);
    else if (i < 14) biasf[i] = ldany(sb1, i - 8, f);
    else if (i < 16) biasf[i] = ldany(ob1, i - 14, f);
    else if (i < 144) biasf[i] = ldany(fb1, i - 16, f);
    else if (i < 208) biasf[i] = ldany(fb2, i - 144, f);
    else biasf[i] = ldany(frb, i - 208, f);
    return;
  }
  i -= 336;
  if (i < 73728) {   // a_h1 permuted (C=128)
    int co = i / 1152, rem = i - co * 1152;
    int t = rem >> 7, ci = rem & 127;
    float v = 0.f;
    if (co < 8) v = ldany(rot_w1, (size_t)co * 1152 + ci * 9 + t, f);
    else if (co < 14) v = ldany(scl_w1, (size_t)(co - 8) * 1152 + ci * 9 + t, f);
    else if (co < 16) v = ldany(opa_w1, (size_t)(co - 14) * 1152 + ci * 9 + t, f);
    a_h1[i] = bfenc(v); return;
  }
  i -= 73728;
  if (i < 147456) {
    int co = i / 1152, rem = i - co * 1152;
    int t = rem >> 7, ci = rem & 127;
    a_fl1[i] = bfenc(ldany(fl_w1, (size_t)co * 1152 + ci * 9 + t, f)); return;
  }
  i -= 147456;
  if (i < 73728) {
    int co = i / 1152, rem = i - co * 1152;
    int t = rem >> 7, ci = rem & 127;
    a_fl2[i] = bfenc(ldany(fl_w2, (size_t)co * 1152 + ci * 9 + t, f)); return;
  }
  i -= 73728;
  if (i < 73728) {
    if (permfr) {
      int co = i / 576, rem = i - co * 576;
      int t = rem >> 6, ci = rem & 63;
      a_fr[i] = bfenc(ldany(fr_w, (size_t)co * 576 + ci * 9 + t, f));
    } else {
      a_fr[i] = bfenc(ldany(fr_w, i, f));
    }
    return;
  }
}

// ---------------- MFMA conv, 4 waves x (16co x 64px) ----------------
template<int OM, int PM, int ACT, bool GUARD, int KP, bool OPX>
__global__ __launch_bounds__(256) void gemm_conv4_k(const unsigned short* __restrict__ A,
    const unsigned short* __restrict__ X, const float* __restrict__ bias,
    void* __restrict__ out, const int* __restrict__ flag, int K, int glim) {
  __shared__ v8s As4[64][5];
  __shared__ v8s Bs4[64][5];
  __shared__ int off9s[64][9];
  const int tid = threadIdx.x;
  const int pxB = blockIdx.x * 64;
  const int coB = blockIdx.y * 64;
  if (tid < 64) {
    int p = pxB + tid;
    int h = p / Ww, w = p - h * Ww;
#pragma unroll
    for (int r = 0; r < 3; r++) {
      int hh = mapidx(h + r - 1, Hh, PM);
#pragma unroll
      for (int s = 0; s < 3; s++)
        off9s[tid][r * 3 + s] = hh * Ww + mapidx(w + s - 1, Ww, PM);
    }
  }
  const int lane = tid & 63, wv = tid >> 6;
  const int m16 = lane & 15, quad = lane >> 4;
  const int srow = tid >> 2, sg = tid & 3;
  v4f acc[4];
#pragma unroll
  for (int b = 0; b < 4; b++) acc[b] = (v4f){0.f, 0.f, 0.f, 0.f};
  __syncthreads();
  const int nIter = K >> 5;
  for (int it = 0; it < nIter; it++) {
    const int k0 = it << 5;
    {
      const unsigned short* ap = &A[(size_t)(coB + srow) * K + k0 + sg * 8];
      v8s av;
#pragma unroll
      for (int j = 0; j < 8; j++) av[j] = (short)ap[j];
      As4[srow][sg] = av;
    }
    {
      v8s bv;
      if (KP == 128) {
        int kk = k0 + sg * 8;
        int t = kk >> 7, c0 = kk & 127;
        const unsigned short* xp = &X[(size_t)off9s[srow][t] * 128 + c0];
#pragma unroll
        for (int j = 0; j < 8; j++) bv[j] = (short)xp[j];
      } else if (KP == 64) {
        int kk = k0 + sg * 8;
        int t = kk >> 6, c0 = kk & 63;
        const unsigned short* xp = &X[(size_t)off9s[srow][t] * 64 + c0];
#pragma unroll
        for (int j = 0; j < 8; j++) bv[j] = (short)xp[j];
      } else {
#pragma unroll
        for (int j = 0; j < 8; j++) {
          int k = k0 + sg * 8 + j;
          int ci = k / 9;
          int t = k - ci * 9;
          bv[j] = (short)X[(size_t)ci * NP + off9s[srow][t]];
        }
      }
      Bs4[srow][sg] = bv;
    }
    __syncthreads();
    v8s af = As4[wv * 16 + m16][quad];
    v8s bfr[4];
#pragma unroll
    for (int b = 0; b < 4; b++) bfr[b] = Bs4[b * 16 + m16][quad];
#pragma unroll
    for (int b = 0; b < 4; b++)
      acc[b] = __builtin_amdgcn_mfma_f32_16x16x32_bf16(af, bfr[b], acc[b], 0, 0, 0);
    __syncthreads();
  }
  const int obf = (OM == 2) ? *flag : (OM == 1);
#pragma unroll
  for (int b = 0; b < 4; b++) {
#pragma unroll
    for (int r = 0; r < 4; r++) {
      int co = coB + wv * 16 + quad * 4 + r;
      int px = pxB + b * 16 + m16;
      if (GUARD && co >= glim) continue;
      float bv = bias[GUARD ? (co & 15) : co];
      float v = acc[b][r] + bv;
      v = (ACT == 2) ? geluf(v) : eluf(v);
      size_t oi = OPX ? ((size_t)px * 128 + co) : ((size_t)co * NP + px);
      if (obf) ((unsigned short*)out)[oi] = bfenc(v);
      else ((float*)out)[oi] = v;
    }
  }
}

// ---------------- fused fl1 + head conv ----------------
__global__ __launch_bounds__(256) void conv_fused1_k(
    const unsigned short* __restrict__ a_fl1, const unsigned short* __restrict__ a_h1,
    const unsigned short* __restrict__ X, const float* __restrict__ biasf,
    unsigned short* __restrict__ t1b, float* __restrict__ h1) {
  __shared__ v8s As4[64][5];
  __shared__ v8s Bs4[64][5];
  __shared__ int off9s[64][9];
  const int tid = threadIdx.x;
  const int zy = blockIdx.y;
  const bool ishead = (zy == 2);
  const int pm = ishead ? 0 : 1;
  const int pxB = blockIdx.x * 64;
  const int coB = ishead ? 0 : zy * 64;
  const unsigned short* A = ishead ? a_h1 : a_fl1;
  if (tid < 64) {
    int p = pxB + tid;
    int h = p / Ww, w = p - h * Ww;
#pragma unroll
    for (int r = 0; r < 3; r++) {
      int hh = mapidx(h + r - 1, Hh, pm);
#pragma unroll
      for (int s = 0; s < 3; s++)
        off9s[tid][r * 3 + s] = hh * Ww + mapidx(w + s - 1, Ww, pm);
    }
  }
  const int lane = tid & 63, wv = tid >> 6;
  const int m16 = lane & 15, quad = lane >> 4;
  const int srow = tid >> 2, sg = tid & 3;
  v4f acc[4];
#pragma unroll
  for (int b = 0; b < 4; b++) acc[b] = (v4f){0.f, 0.f, 0.f, 0.f};
  __syncthreads();
  for (int it = 0; it < 36; it++) {
    const int k0 = it << 5;
    {
      const unsigned short* ap = &A[(size_t)(coB + srow) * 1152 + k0 + sg * 8];
      v8s av;
#pragma unroll
      for (int j = 0; j < 8; j++) av[j] = (short)ap[j];
      As4[srow][sg] = av;
    }
    {
      int kk = k0 + sg * 8;
      int t = kk >> 7, c0 = kk & 127;
      const unsigned short* xp = &X[(size_t)off9s[srow][t] * 128 + c0];
      v8s bv;
#pragma unroll
      for (int j = 0; j < 8; j++) bv[j] = (short)xp[j];
      Bs4[srow][sg] = bv;
    }
    __syncthreads();
    v8s af = As4[wv * 16 + m16][quad];
    v8s bfr[4];
#pragma unroll
    for (int b = 0; b < 4; b++) bfr[b] = Bs4[b * 16 + m16][quad];
#pragma unroll
    for (int b = 0; b < 4; b++)
      acc[b] = __builtin_amdgcn_mfma_f32_16x16x32_bf16(af, bfr[b], acc[b], 0, 0, 0);
    __syncthreads();
  }
#pragma unroll
  for (int b = 0; b < 4; b++) {
#pragma unroll
    for (int r = 0; r < 4; r++) {
      int co = coB + wv * 16 + quad * 4 + r;
      int px = pxB + b * 16 + m16;
      if (ishead) {
        if (co < 16) h1[(size_t)co * NP + px] = geluf(acc[b][r] + biasf[co]);
      } else {
        t1b[(size_t)px * 128 + co] = bfenc(eluf(acc[b][r] + biasf[16 + co]));
      }
    }
  }
}

// ---------------- head2 + per-gaussian prep ----------------
__global__ __launch_bounds__(64) void head2_prep_k(const float* __restrict__ h1,
    const float* __restrict__ smallf, const float* __restrict__ dispf,
    float* __restrict__ params, float* __restrict__ zbuf, int* __restrict__ rank) {
  const float* invK = smallf;
  const float* Km   = smallf + 16;
  const float* rw2  = smallf + 32;
  const float* rb2  = smallf + 320;
  const float* sw2  = smallf + 324;
  const float* sb2  = smallf + 486;
  const float* ow2  = smallf + 489;
  const float* ob2  = smallf + 507;
  int p = blockIdx.x * 64 + threadIdx.x;
  if (p >= NP) return;
  int hh = p / Ww, ww = p - hh * Ww;
  float racc[4], sacc[3], oacc;
#pragma unroll
  for (int i = 0; i < 4; i++) racc[i] = rb2[i];
#pragma unroll
  for (int i = 0; i < 3; i++) sacc[i] = sb2[i];
  oacc = ob2[0];
  for (int ci = 0; ci < 16; ci++) {
    float t9[9];
#pragma unroll
    for (int r = 0; r < 3; r++) {
      int rr = mapidx(hh + r - 1, Hh, 0);
#pragma unroll
      for (int s = 0; s < 3; s++) {
        int cc = mapidx(ww + s - 1, Ww, 0);
        t9[r * 3 + s] = h1[(size_t)ci * NP + rr * Ww + cc];
      }
    }
    if (ci < 8) {
      for (int co = 0; co < 4; co++)
#pragma unroll
        for (int k = 0; k < 9; k++)
          racc[co] = fmaf(t9[k], rw2[(co * 8 + ci) * 9 + k], racc[co]);
    } else if (ci < 14) {
      int c2 = ci - 8;
      for (int co = 0; co < 3; co++)
#pragma unroll
        for (int k = 0; k < 9; k++)
          sacc[co] = fmaf(t9[k], sw2[(co * 6 + c2) * 9 + k], sacc[co]);
    } else {
      int c2 = ci - 14;
#pragma unroll
      for (int k = 0; k < 9; k++)
        oacc = fmaf(t9[k], ow2[c2 * 9 + k], oacc);
    }
  }
  float nq = sqrtf(racc[0]*racc[0] + racc[1]*racc[1] + racc[2]*racc[2] + racc[3]*racc[3]);
  nq = fmaxf(nq, 1e-12f);
  float qw = racc[0] / nq, qx = racc[1] / nq, qy = racc[2] / nq, qz = racc[3] / nq;
  float s0 = fabsf(sacc[0]), s1 = fabsf(sacc[1]), s2 = fabsf(sacc[2]);
  float opa = 1.f / (1.f + __expf(-oacc));
  float d = dispf[p];
  float scaled = 0.01f + 9.99f * d;
  float depth = fminf(fmaxf(1.f / scaled, 0.1f), 100.f);
  float M00 = invK[0], M01 = invK[1], M02 = invK[2];
  float M10 = invK[4], M11 = invK[5], M12 = invK[6];
  float M20 = invK[8], M21 = invK[9], M22 = invK[10];
  float gxf = (float)ww, gyf = (float)hh;
  float X = (M00 * gxf + M01 * gyf + M02) * depth;
  float Y = (M10 * gxf + M11 * gyf + M12) * depth;
  float Z = (M20 * gxf + M21 * gyf + M22) * depth;
  float fxk = Km[0], fyk = Km[5];
  float cxk = Km[2], cyk = Km[6];
  float u = fxk * X / Z + cxk;
  float v = fyk * Y / Z + cyk;
  float R00 = 1.f - 2.f*(qy*qy + qz*qz), R01 = 2.f*(qx*qy - qw*qz), R02 = 2.f*(qx*qz + qw*qy);
  float R10 = 2.f*(qx*qy + qw*qz), R11 = 1.f - 2.f*(qx*qx + qz*qz), R12 = 2.f*(qy*qz - qw*qx);
  float R20 = 2.f*(qx*qz - qw*qy), R21 = 2.f*(qy*qz + qw*qx), R22 = 1.f - 2.f*(qx*qx + qy*qy);
  float M0a = R00*s0, M0b = R01*s1, M0c = R02*s2;
  float M1a = R10*s0, M1b = R11*s1, M1c = R12*s2;
  float M2a = R20*s0, M2b = R21*s1, M2c = R22*s2;
  float S00 = M0a*M0a + M0b*M0b + M0c*M0c;
  float S01 = M0a*M1a + M0b*M1b + M0c*M1c;
  float S02 = M0a*M2a + M0b*M2b + M0c*M2c;
  float S11 = M1a*M1a + M1b*M1b + M1c*M1c;
  float S12 = M1a*M2a + M1b*M2b + M1c*M2c;
  float S22 = M2a*M2a + M2b*M2b + M2c*M2c;
  float iz = 1.f / Z;
  float j00 = fxk * iz, j02 = -fxk * X * iz * iz;
  float j11 = fyk * iz, j12 = -fyk * Y * iz * iz;
  float c00 = j00*j00*S00 + 2.f*j00*j02*S02 + j02*j02*S22 + 0.3f;
  float c01 = j00*j11*S01 + j00*j12*S02 + j02*j11*S12 + j02*j12*S22;
  float c11 = j11*j11*S11 + 2.f*j11*j12*S12 + j12*j12*S22 + 0.3f;
  float det = c00 * c11 - c01 * c01;
  float idet = 1.f / det;
  float* pr = params + (size_t)p * 8;
  pr[0] = u; pr[1] = v; pr[2] = c11 * idet; pr[3] = -c01 * idet;
  pr[4] = c00 * idet; pr[5] = opa; pr[6] = Z; pr[7] = 0.f;
  zbuf[p] = Z;
  rank[p] = 0;
}

// ---------------- rank-by-count stable argsort ----------------
__global__ __launch_bounds__(256) void rank_count_k(const float* __restrict__ zbuf,
                                                    int* __restrict__ rank) {
  int i = blockIdx.x * 256 + threadIdx.x;
  int sid = blockIdx.y;
  float zi = zbuf[i];
  const float4* zv = (const float4*)(zbuf + sid * 960);
  int cnt = 0;
  for (int t = 0; t < 240; t++) {
    float4 z4 = zv[t];
    int jb = sid * 960 + t * 4;
    cnt += (z4.x < zi || (z4.x == zi && jb + 0 < i)) ? 1 : 0;
    cnt += (z4.y < zi || (z4.y == zi && jb + 1 < i)) ? 1 : 0;
    cnt += (z4.z < zi || (z4.z == zi && jb + 2 < i)) ? 1 : 0;
    cnt += (z4.w < zi || (z4.w == zi && jb + 3 < i)) ? 1 : 0;
  }
  atomicAdd(&rank[i], cnt);
}

__global__ __launch_bounds__(256) void scatter_k(const int* __restrict__ rank,
                                                 int* __restrict__ ord) {
  int i = blockIdx.x * 256 + threadIdx.x;
  ord[rank[i]] = i;
}

// ---------------- fused gather (non-atomic): featT bf16 + params (raw) ----------------
__global__ __launch_bounds__(256) void gather_all_k(const int* __restrict__ ord,
    const float* __restrict__ t2e, const float* __restrict__ params,
    unsigned short* __restrict__ featT, float* __restrict__ params_s) {
  int gid = blockIdx.x * 256 + threadIdx.x;
  if (gid < NP * 64) {
    int c = gid / NP, n = gid - c * NP;
    featT[gid] = bfenc(t2e[(size_t)c * NP + ord[n]]);
  } else {
    int g2 = gid - NP * 64;
    int n = g2 >> 3, c = g2 & 7;
    params_s[g2] = params[((size_t)ord[n] << 3) + c];
  }
}

// ---------------- gather (atomic fallback) ----------------
__global__ __launch_bounds__(256) void gather_k(const int* __restrict__ ord,
    const float* __restrict__ params, const float* __restrict__ t2e,
    float* __restrict__ params_s, float* __restrict__ feat_s, float* levz) {
  int gid = blockIdx.x * 256 + threadIdx.x;   // NP*64
  int n = gid >> 6, c = gid & 63;
  int orig = ord[n];
  feat_s[gid] = t2e[(size_t)c * NP + orig];
  if (levz) levz[gid] = 0.f;
  if (c < 8) params_s[(n << 3) + c] = params[((size_t)orig << 3) + c];
}

// ---------------- MFMA raster: 2 indep waves/block, R16-proven alpha path ----------------
// grid (NP/128, NCH), block 128. partial [chunk][px][64ch]; tch[chunk][px].
__global__ __launch_bounds__(128) void raster_mfma_k(const float* __restrict__ params_s,
    const unsigned short* __restrict__ featT, float* __restrict__ partial,
    float* __restrict__ tch) {
  __shared__ unsigned int Wl[2][64][17];
  const int tid = threadIdx.x;
  const int lane = tid & 63, wv = tid >> 6;
  const int m16 = lane & 15, quad = lane >> 4;
  const int ch = blockIdx.y;
  const int g0 = ch * CSZ;
  const int pxB = blockIdx.x * 128;
  const int mypx = pxB + wv * 64 + lane;
  const float px = (float)(mypx % Ww), py = (float)(mypx / Ww);
  float T = 1.f;
  v4f acc[4][4];
#pragma unroll
  for (int a = 0; a < 4; a++)
#pragma unroll
    for (int b = 0; b < 4; b++) acc[a][b] = (v4f){0.f, 0.f, 0.f, 0.f};
  const float4* pv = (const float4*)params_s + (size_t)g0 * 2;
  for (int sub = 0; sub < CSZ / 32; sub++) {
    float al[32];
#pragma unroll
    for (int j = 0; j < 32; j++) {
      float4 pa = pv[(sub * 32 + j) * 2], pb = pv[(sub * 32 + j) * 2 + 1];
      float dx = px - pa.x, dy = py - pa.y;
      float power = -0.5f * (pa.z * dx * dx + pb.x * dy * dy) - pa.w * dx * dy;
      al[j] = fminf(pb.y * __expf(power), 0.99f);
    }
#pragma unroll
    for (int jj = 0; jj < 16; jj++) {
      float w0 = al[2 * jj] * T;     T *= 1.f - al[2 * jj];
      float w1 = al[2 * jj + 1] * T; T *= 1.f - al[2 * jj + 1];
      Wl[wv][lane][jj] = (unsigned)bfenc(w0) | ((unsigned)bfenc(w1) << 16);
    }
    v8s af[4], bfr[4];
#pragma unroll
    for (int a = 0; a < 4; a++) {
      unsigned d0 = Wl[wv][a * 16 + m16][quad * 4 + 0];
      unsigned d1 = Wl[wv][a * 16 + m16][quad * 4 + 1];
      unsigned d2 = Wl[wv][a * 16 + m16][quad * 4 + 2];
      unsigned d3 = Wl[wv][a * 16 + m16][quad * 4 + 3];
      v8s t;
      t[0] = (short)(d0 & 0xffff); t[1] = (short)(d0 >> 16);
      t[2] = (short)(d1 & 0xffff); t[3] = (short)(d1 >> 16);
      t[4] = (short)(d2 & 0xffff); t[5] = (short)(d2 >> 16);
      t[6] = (short)(d3 & 0xffff); t[7] = (short)(d3 >> 16);
      af[a] = t;
    }
#pragma unroll
    for (int b = 0; b < 4; b++) {
      const unsigned short* fp = &featT[(size_t)(b * 16 + m16) * NP + g0 + sub * 32 + quad * 8];
      v8s t;
#pragma unroll
      for (int j = 0; j < 8; j++) t[j] = (short)fp[j];
      bfr[b] = t;
    }
#pragma unroll
    for (int a = 0; a < 4; a++)
#pragma unroll
      for (int b = 0; b < 4; b++)
        acc[a][b] = __builtin_amdgcn_mfma_f32_16x16x32_bf16(af[a], bfr[b], acc[a][b], 0, 0, 0);
  }
  float* pbase = partial + (size_t)ch * NP * 64 + (size_t)(pxB + wv * 64) * 64;
#pragma unroll
  for (int a = 0; a < 4; a++) {
#pragma unroll
    for (int b = 0; b < 4; b++) {
#pragma unroll
      for (int r = 0; r < 4; r++) {
        pbase[(size_t)(a * 16 + quad * 4 + r) * 64 + b * 16 + m16] = acc[a][b][r];
      }
    }
  }
  tch[(size_t)ch * NP + mypx] = T;
}

// ---------------- alpha (atomic fallback only) ----------------
__global__ __launch_bounds__(256) void alpha_k(const float* __restrict__ params_s,
    float* __restrict__ tch, int chsz) {
  const int p = blockIdx.x * 256 + threadIdx.x;
  const int ch = blockIdx.y;
  const float px = (float)(p % Ww), py = (float)(p / Ww);
  float T = 1.f;
  const float4* pv = (const float4*)params_s + (size_t)ch * chsz * 2;
  for (int n0 = 0; n0 < chsz; n0++) {
    float4 pa = pv[n0 * 2], pb = pv[n0 * 2 + 1];
    float dx = px - pa.x, dy = py - pa.y;
    float power = -0.5f * (pa.z * dx * dx + pb.x * dy * dy) - pa.w * dx * dy;
    float al = fminf(pb.y * __expf(power), 0.99f);
    T *= 1.f - al;
  }
  tch[(size_t)ch * NP + p] = T;
}

// ---------------- prefix products (atomic fallback only) ----------------
__global__ __launch_bounds__(256) void tpre_k(const float* __restrict__ tch,
    float* __restrict__ tpre, int nchunk) {
  int p = blockIdx.x * 256 + threadIdx.x;
  float T = 1.f;
  for (int ch = 0; ch < nchunk; ch++) {
    tpre[(size_t)ch * NP + p] = T;
    T *= tch[(size_t)ch * NP + p];
  }
}

// ---------------- atomic-fallback raster ----------------
__global__ __launch_bounds__(128) void raster_atomic_k(const float* __restrict__ params_s,
    const float* __restrict__ feat_s, const float* __restrict__ tpre,
    float* __restrict__ lev, int chsz) {
  const int p = blockIdx.x * 128 + threadIdx.x;
  const int ch = blockIdx.y;
  const float px = (float)(p % Ww), py = (float)(p / Ww);
  float4 acc[16];
#pragma unroll
  for (int q = 0; q < 16; q++) acc[q] = make_float4(0.f, 0.f, 0.f, 0.f);
  float T = 1.f;
  const int g0 = ch * chsz;
  const float4* pv = (const float4*)params_s + (size_t)g0 * 2;
  for (int n0 = 0; n0 < chsz; n0++) {
    float4 pa = pv[n0 * 2], pb = pv[n0 * 2 + 1];
    float dx = px - pa.x, dy = py - pa.y;
    float power = -0.5f * (pa.z * dx * dx + pb.x * dy * dy) - pa.w * dx * dy;
    float al = fminf(pb.y * __expf(power), 0.99f);
    float wgt = al * T;
    T *= 1.f - al;
    const float4* fr = (const float4*)(feat_s + (((size_t)(g0 + n0)) << 6));
#pragma unroll
    for (int q = 0; q < 16; q++) {
      float4 f = fr[q];
      acc[q].x = fmaf(wgt, f.x, acc[q].x);
      acc[q].y = fmaf(wgt, f.y, acc[q].y);
      acc[q].z = fmaf(wgt, f.z, acc[q].z);
      acc[q].w = fmaf(wgt, f.w, acc[q].w);
    }
  }
  float Ts = tpre[(size_t)ch * NP + p];
#pragma unroll
  for (int q = 0; q < 16; q++) {
    atomicAdd(&lev[(size_t)(q * 4 + 0) * NP + p], Ts * acc[q].x);
    atomicAdd(&lev[(size_t)(q * 4 + 1) * NP + p], Ts * acc[q].y);
    atomicAdd(&lev[(size_t)(q * 4 + 2) * NP + p], Ts * acc[q].z);
    atomicAdd(&lev[(size_t)(q * 4 + 3) * NP + p], Ts * acc[q].w);
  }
}

// ---------------- combine with inline prefix -> px-major bf16 levb ----------------
__global__ __launch_bounds__(256) void combine_k(const float* __restrict__ partial,
    const float* __restrict__ tch, unsigned short* __restrict__ levb) {
  int gid = blockIdx.x * 256 + threadIdx.x;   // 64*NP, gid = p*64 + c
  int p = gid >> 6;
  float T = 1.f, s = 0.f;
  for (int ch = 0; ch < NCH; ch++) {
    s = fmaf(T, partial[(size_t)ch * NP * 64 + gid], s);
    T *= tch[(size_t)ch * NP + p];
  }
  levb[gid] = bfenc(s);
}

// ---------------- lev fp32 -> ch-major bf16 (atomic path) ----------------
__global__ __launch_bounds__(256) void cvt_lev_k(const float* __restrict__ lev,
                                                 unsigned short* __restrict__ levb) {
  int i = blockIdx.x * 256 + threadIdx.x;
  levb[i] = bfenc(lev[i]);
}

extern "C" void kernel_launch(void* const* d_in, const int* in_sizes, int n_in,
                              void* d_out, int out_size, void* d_ws, size_t ws_size,
                              hipStream_t stream) {
  (void)in_sizes; (void)n_in; (void)out_size;
  const void* init_feature = d_in[0];
  const void* disp   = d_in[1];
  const void* invK   = d_in[2];
  const void* Km     = d_in[3];
  const void* rot_w1 = d_in[4];
  const void* rot_b1 = d_in[5];
  const void* rot_w2 = d_in[6];
  const void* rot_b2 = d_in[7];
  const void* scl_w1 = d_in[8];
  const void* scl_b1 = d_in[9];
  const void* scl_w2 = d_in[10];
  const void* scl_b2 = d_in[11];
  const void* opa_w1 = d_in[12];
  const void* opa_b1 = d_in[13];
  const void* opa_w2 = d_in[14];
  const void* opa_b2 = d_in[15];
  const void* fl_w1  = d_in[16];
  const void* fl_b1  = d_in[17];
  const void* fl_w2  = d_in[18];
  const void* fl_b2  = d_in[19];
  const void* fr_w   = d_in[20];
  const void* fr_b   = d_in[21];

  float* wsf = (float*)d_ws;
  int*   flag    = (int*)wsf;                   // @0        16
  float* smallf  = wsf + 16;                    // 512
  float* dispf   = wsf + 528;                   // 7680
  float* biasf   = wsf + 8208;                  // 512
  unsigned short* a_h1  = (unsigned short*)(wsf + 8720);    // 36864 f
  unsigned short* a_fl1 = (unsigned short*)(wsf + 45584);   // 73728 f
  unsigned short* a_fl2 = (unsigned short*)(wsf + 119312);  // 36864 f
  unsigned short* a_fr  = (unsigned short*)(wsf + 156176);  // 36864 f
  unsigned short* xb    = (unsigned short*)(wsf + 193040);  // 491520 f
  unsigned short* t1b   = (unsigned short*)(wsf + 684560);  // 491520 f ([px][128])
  float* t2e     = wsf + 1176080;               // 491520 ([c][px])
  float* h1      = wsf + 1667600;               // 122880
  float* params  = wsf + 1790480;               // 61440
  float* params_s= wsf + 1851920;               // 61440
  float* featbuf = wsf + 1913360;               // 491520 (featT bf16 | feat_s fp32)
  float* tch     = wsf + 2404880;               // 245760
  float* tpre    = wsf + 2650640;               // 245760 (fallback only)
  unsigned short* levb = (unsigned short*)(wsf + 2896400);  // 245760 f
  float* zbuf    = wsf + 3142160;               // 7680
  int*   rank    = (int*)(wsf + 3149840);       // 7680
  int*   ord     = (int*)(wsf + 3157520);       // 7680
  float* lev     = wsf + 3165200;               // 491520 (atomic) / partial base
  float* partial = lev;                         // non-atomic: NCH*64*NP f

  const size_t needNA = (size_t)(3165200 + (size_t)NCH * 64 * NP) * 4;  // 71.6 MB
  const int nonatomic = (ws_size >= needNA) ? 1 : 0;

  sniff_k<<<1, 256, 0, stream>>>((const unsigned short*)fl_w1, flag);
  transpose_x_k<<<dim3(240, 4), 256, 0, stream>>>(flag, init_feature, xb);
  prep_k<<<1474, 256, 0, stream>>>(flag,
      disp, invK, Km, rot_w2, rot_b2, scl_w2, scl_b2, opa_w2, opa_b2,
      rot_b1, scl_b1, opa_b1, fl_b1, fl_b2, fr_b,
      rot_w1, scl_w1, opa_w1, fl_w1, fl_w2, fr_w,
      dispf, smallf, biasf, a_h1, a_fl1, a_fl2, a_fr, nonatomic);

  // fused fl1 + head conv (one dispatch), then fl2
  conv_fused1_k<<<dim3(120, 3), 256, 0, stream>>>(a_fl1, a_h1, xb, biasf, t1b, h1);
  gemm_conv4_k<0, 1, 1, false, 128, false><<<dim3(120, 1), 256, 0, stream>>>(
      a_fl2, t1b, biasf + 144, t2e, flag, 1152, 64);
  head2_prep_k<<<120, 64, 0, stream>>>(h1, smallf, dispf, params, zbuf, rank);
  rank_count_k<<<dim3(30, 8), 256, 0, stream>>>(zbuf, rank);
  scatter_k<<<30, 256, 0, stream>>>(rank, ord);

  if (nonatomic) {
    gather_all_k<<<(NP * 72) / 256, 256, 0, stream>>>(ord, t2e, params,
        (unsigned short*)featbuf, params_s);
    raster_mfma_k<<<dim3(NP / 128, NCH), 128, 0, stream>>>(params_s,
        (const unsigned short*)featbuf, partial, tch);
    combine_k<<<(NP * 64) / 256, 256, 0, stream>>>(partial, tch, levb);
    gemm_conv4_k<2, 1, 1, false, 64, false><<<dim3(120, 2), 256, 0, stream>>>(
        a_fr, levb, biasf + 208, d_out, flag, 576, 128);
  } else {
    gather_k<<<(NP * 64) / 256, 256, 0, stream>>>(ord, params, t2e, params_s,
                                                  featbuf, lev);
    alpha_k<<<dim3(NP / 256, 32), 256, 0, stream>>>(params_s, tch, 240);
    tpre_k<<<30, 256, 0, stream>>>(tch, tpre, 32);
    raster_atomic_k<<<dim3(NP / 128, 32), 128, 0, stream>>>(params_s, featbuf,
                                                            tpre, lev, 240);
    cvt_lev_k<<<1920, 256, 0, stream>>>(lev, levb);
    gemm_conv4_k<2, 1, 1, false, 0, false><<<dim3(120, 2), 256, 0, stream>>>(
        a_fr, levb, biasf + 208, d_out, flag, 576, 128);
  }
}